// Round 4
// baseline (15392.270 us; speedup 1.0000x reference)
//
#include <hip/hip_runtime.h>

static constexpr int KN  = 256;   // codebook entries
static constexpr int DD  = 384;   // feature dim
static constexpr int DD4 = 96;    // DD/4
static constexpr int TM  = 64;    // rows per block
static constexpr int DK  = 32;    // D-chunk per LDS stage
#define FLAG_MARGIN 0.005f
#define CAND_MARGIN 0.004f

// ======== numpy-fp32 emulation helpers (no FMA contraction possible) ========

// np.sum(p*p, axis=-1), n=384: pairwise 384->(96+96)+(96+96);
// 96-block = 8 scalar accumulators, tree ((r0+r1)+(r2+r3))+((r4+r5)+(r6+r7))
__device__ __forceinline__ float emu_sq_pairwise384(const float* __restrict__ p) {
  float S[4];
#pragma unroll
  for (int blk = 0; blk < 4; ++blk) {
    const float* b = p + blk * 96;
    float r[8];
#pragma unroll
    for (int l = 0; l < 8; ++l) r[l] = __fmul_rn(b[l], b[l]);
    for (int j = 8; j < 96; j += 8) {
#pragma unroll
      for (int l = 0; l < 8; ++l) r[l] = __fadd_rn(r[l], __fmul_rn(b[j + l], b[j + l]));
    }
    float t1 = __fadd_rn(__fadd_rn(r[0], r[1]), __fadd_rn(r[2], r[3]));
    float t2 = __fadd_rn(__fadd_rn(r[4], r[5]), __fadd_rn(r[6], r[7]));
    S[blk] = __fadd_rn(t1, t2);
  }
  return __fadd_rn(__fadd_rn(S[0], S[1]), __fadd_rn(S[2], S[3]));
}

// Modern numpy (>=1.21) einsum sum_of_products_contig_two, SSE baseline:
// 4 vector accumulators x 4 lanes, muladd = mul+add (2 roundings),
// combine (acc0+acc1)+(acc2+acc3), then SSE3 hadd tree (w0+w1)+(w2+w3).
__device__ __forceinline__ float emu_dot384_np(const float* __restrict__ x,
                                               const float* __restrict__ c) {
  float s[16];
#pragma unroll
  for (int t = 0; t < 16; ++t) s[t] = 0.f;
  for (int j = 0; j < 384; j += 16) {
#pragma unroll
    for (int t = 0; t < 16; ++t)
      s[t] = __fadd_rn(__fmul_rn(x[j + t], c[j + t]), s[t]);
  }
  float w0 = __fadd_rn(__fadd_rn(s[0], s[4]), __fadd_rn(s[8],  s[12]));
  float w1 = __fadd_rn(__fadd_rn(s[1], s[5]), __fadd_rn(s[9],  s[13]));
  float w2 = __fadd_rn(__fadd_rn(s[2], s[6]), __fadd_rn(s[10], s[14]));
  float w3 = __fadd_rn(__fadd_rn(s[3], s[7]), __fadd_rn(s[11], s[15]));
  return __fadd_rn(__fadd_rn(w0, w1), __fadd_rn(w2, w3));
}

// ---------------- codebook squared norms (fast prescreen only) ----------------
__global__ void cb_norms_kernel(const float* __restrict__ cb0,
                                const float* __restrict__ cb1,
                                const float* __restrict__ cb2,
                                float* __restrict__ e2) {
  int l = blockIdx.x;
  int k = threadIdx.x;
  const float* cb = (l == 0) ? cb0 : ((l == 1) ? cb1 : cb2);
  const float4* c4 = reinterpret_cast<const float4*>(cb + (size_t)k * DD);
  double s = 0.0;
#pragma unroll 8
  for (int i = 0; i < DD4; ++i) {
    float4 v = c4[i];
    s += (double)v.x * v.x + (double)v.y * v.y + (double)v.z * v.z + (double)v.w * v.w;
  }
  e2[l * KN + k] = (float)s;
}

// ---------------- main VQ kernel ----------------
// Block: 256 threads. Tile: TM=64 rows x all K=256 cols.
// Thread (rg,cg): rg=tid>>4 owns rows rg*4..rg*4+3; cg=tid&15 owns cols cg+16*c.
__global__ __launch_bounds__(256) void vq_kernel(
    const float* __restrict__ X,
    const float* __restrict__ CB,
    const float* __restrict__ E2,
    float* __restrict__ Q,
    float* __restrict__ IDXO,
    double* __restrict__ PART)
{
  __shared__ float As[TM][36];
  __shared__ float Bs[KN][36];
  __shared__ int idx_s[TM];
  __shared__ double wred[4];

  const int tid = threadIdx.x;
  const int rg = tid >> 4;
  const int cg = tid & 15;
  const size_t row0 = (size_t)blockIdx.x * TM;

  const float4* X4  = reinterpret_cast<const float4*>(X);
  const float4* CB4 = reinterpret_cast<const float4*>(CB);
  float4* Q4 = reinterpret_cast<float4*>(Q);

  float acc[4][16];
#pragma unroll
  for (int j = 0; j < 4; ++j)
#pragma unroll
    for (int c = 0; c < 16; ++c) acc[j][c] = 0.f;

  for (int d0 = 0; d0 < DD; d0 += DK) {
    const int dq = d0 >> 2;
#pragma unroll
    for (int s = 0; s < 2; ++s) {
      int i = tid + s * 256;
      int r = i >> 3, f = i & 7;
      float4 v = X4[(row0 + (size_t)r) * DD4 + dq + f];
      *reinterpret_cast<float4*>(&As[r][4 * f]) = v;
    }
#pragma unroll
    for (int s = 0; s < 8; ++s) {
      int i = tid + s * 256;
      int k = i >> 3, f = i & 7;
      *reinterpret_cast<float4*>(&Bs[k][4 * f]) = CB4[(size_t)k * DD4 + dq + f];
    }
    __syncthreads();

#pragma unroll
    for (int d = 0; d < DK; d += 4) {
      float4 a0 = *reinterpret_cast<const float4*>(&As[rg * 4 + 0][d]);
      float4 a1 = *reinterpret_cast<const float4*>(&As[rg * 4 + 1][d]);
      float4 a2 = *reinterpret_cast<const float4*>(&As[rg * 4 + 2][d]);
      float4 a3 = *reinterpret_cast<const float4*>(&As[rg * 4 + 3][d]);
#pragma unroll
      for (int c = 0; c < 16; ++c) {
        float4 b = *reinterpret_cast<const float4*>(&Bs[cg + 16 * c][d]);
        acc[0][c] += a0.x * b.x + a0.y * b.y + a0.z * b.z + a0.w * b.w;
        acc[1][c] += a1.x * b.x + a1.y * b.y + a1.z * b.z + a1.w * b.w;
        acc[2][c] += a2.x * b.x + a2.y * b.y + a2.z * b.z + a2.w * b.w;
        acc[3][c] += a3.x * b.x + a3.y * b.y + a3.z * b.z + a3.w * b.w;
      }
    }
    __syncthreads();
  }

  float my_e2[16];
#pragma unroll
  for (int c = 0; c < 16; ++c) my_e2[c] = E2[cg + 16 * c];

#pragma unroll 1
  for (int j = 0; j < 4; ++j) {
    // ---- pass 1: global min (first-index tie-break) ----
    float b1 = 1e30f; int i1 = 0x7fffffff;
#pragma unroll
    for (int c = 0; c < 16; ++c) {
      int col = cg + 16 * c;
      float sc = my_e2[c] - 2.0f * acc[j][c];
      if (sc < b1 || (sc == b1 && col < i1)) { b1 = sc; i1 = col; }
    }
#pragma unroll
    for (int m = 1; m < 16; m <<= 1) {
      float ob = __shfl_xor(b1, m);
      int   oi = __shfl_xor(i1, m);
      if (ob < b1 || (ob == b1 && oi < i1)) { b1 = ob; i1 = oi; }
    }
    // ---- pass 2: runner-up value (for the flag test) ----
    float b2 = 1e30f;
#pragma unroll
    for (int c = 0; c < 16; ++c) {
      int col = cg + 16 * c;
      if (col == i1) continue;
      float sc = my_e2[c] - 2.0f * acc[j][c];
      if (sc < b2) b2 = sc;
    }
#pragma unroll
    for (int m = 1; m < 16; m <<= 1) {
      float ob = __shfl_xor(b2, m);
      if (ob < b2) b2 = ob;
    }

    int chosen = i1;
    if (b2 - b1 < FLAG_MARGIN) {
      // near-tie: resolve with numpy-fp32 emulated scores
      const size_t r = row0 + (size_t)(rg * 4 + j);
      const float* xr = X + r * DD;
      const float xx = emu_sq_pairwise384(xr);   // same value in all 16 lanes

      float best = 1e30f; int bidx = 0x7fffffff;
      for (int c = 0; c < 16; ++c) {
        int col = cg + 16 * c;
        float scf = my_e2[c] - 2.0f * acc[j][c];
        if (scf <= b1 + CAND_MARGIN) {
          const float* ck = CB + (size_t)col * DD;
          float e2k = emu_sq_pairwise384(ck);
          float E   = emu_dot384_np(xr, ck);
          // d2 = fl( fl(xx - fl(2*E)) + e2 )  — numpy's association order (2*E exact)
          float s = __fadd_rn(__fsub_rn(xx, __fmul_rn(2.0f, E)), e2k);
          if (s < best || (s == best && col < bidx)) { best = s; bidx = col; }
        }
      }
#pragma unroll
      for (int m = 1; m < 16; m <<= 1) {
        float ob = __shfl_xor(best, m);
        int   oi = __shfl_xor(bidx, m);
        if (ob < best || (ob == best && oi < bidx)) { best = ob; bidx = oi; }
      }
      chosen = bidx;
    }
    if (cg == 0) idx_s[rg * 4 + j] = chosen;
  }
  __syncthreads();

  // ---- outputs: idx (as float), q = cb[idx], loss partial ----
  if (tid < TM) IDXO[row0 + tid] = (float)idx_s[tid];

  float lsum = 0.f;
  for (int i = tid; i < TM * DD4; i += 256) {
    int r = i / DD4;
    int c = i - r * DD4;
    int k = idx_s[r];
    float4 qv = CB4[(size_t)k * DD4 + c];
    float4 xv = X4[(row0 + (size_t)r) * DD4 + c];
    float dx = qv.x - xv.x, dy = qv.y - xv.y, dz = qv.z - xv.z, dw = qv.w - xv.w;
    lsum += dx * dx + dy * dy + dz * dz + dw * dw;
    Q4[(row0 + (size_t)r) * DD4 + c] = qv;
  }
#pragma unroll
  for (int m = 1; m < 64; m <<= 1) lsum += __shfl_xor(lsum, m);
  if ((tid & 63) == 0) wred[tid >> 6] = (double)lsum;
  __syncthreads();
  if (tid == 0) PART[blockIdx.x] = wred[0] + wred[1] + wred[2] + wred[3];
}

// ---------------- loss finalize ----------------
__global__ void finalize_kernel(const double* __restrict__ p0, int n0, double w0,
                                const double* __restrict__ p1, int n1, double w1,
                                const double* __restrict__ p2, int n2, double w2,
                                float* __restrict__ out) {
  __shared__ double red[4];
  int tid = threadIdx.x;
  double s0 = 0.0, s1 = 0.0, s2 = 0.0;
  for (int i = tid; i < n0; i += 256) s0 += p0[i];
  for (int i = tid; i < n1; i += 256) s1 += p1[i];
  for (int i = tid; i < n2; i += 256) s2 += p2[i];
  double v = s0 * w0 + s1 * w1 + s2 * w2;
#pragma unroll
  for (int m = 1; m < 64; m <<= 1) v += __shfl_xor(v, m);
  if ((tid & 63) == 0) red[tid >> 6] = v;
  __syncthreads();
  if (tid == 0) out[0] = (float)(red[0] + red[1] + red[2] + red[3]);
}

extern "C" void kernel_launch(void* const* d_in, const int* in_sizes, int n_in,
                              void* d_out, int out_size, void* d_ws, size_t ws_size,
                              hipStream_t stream) {
  const float* l0  = (const float*)d_in[0];
  const float* l1  = (const float*)d_in[1];
  const float* l2  = (const float*)d_in[2];
  const float* cb0 = (const float*)d_in[3];
  const float* cb1 = (const float*)d_in[4];
  const float* cb2 = (const float*)d_in[5];

  const size_t n_q0 = (size_t)in_sizes[0];
  const size_t n_q1 = (size_t)in_sizes[1];
  const size_t n_q2 = (size_t)in_sizes[2];
  const int r0 = (int)(n_q0 / DD);   // 65536
  const int r1 = (int)(n_q1 / DD);   // 262144
  const int r2 = (int)(n_q2 / DD);   // 262144

  float* out   = (float*)d_out;
  float* q0    = out;
  float* q1    = q0 + n_q0;
  float* q2    = q1 + n_q1;
  float* lossp = q2 + n_q2;
  float* idx0  = lossp + 1;
  float* idx1  = idx0 + r0;
  float* idx2  = idx1 + r1;

  float* e2     = (float*)d_ws;                       // 3*256 fp32
  double* part  = (double*)((char*)d_ws + 4096);
  const int nb0 = r0 / TM, nb1 = r1 / TM, nb2 = r2 / TM;
  double* p0 = part;
  double* p1 = p0 + nb0;
  double* p2 = p1 + nb1;

  cb_norms_kernel<<<3, 256, 0, stream>>>(cb0, cb1, cb2, e2);

  vq_kernel<<<nb0, 256, 0, stream>>>(l0, cb0, e2 + 0 * KN, q0, idx0, p0);
  vq_kernel<<<nb1, 256, 0, stream>>>(l1, cb1, e2 + 1 * KN, q1, idx1, p1);
  vq_kernel<<<nb2, 256, 0, stream>>>(l2, cb2, e2 + 2 * KN, q2, idx2, p2);

  const double w0 = 0.05 / ((double)r0 * DD);
  const double w1 = 0.25 / ((double)r1 * DD);
  const double w2 = 0.60 / ((double)r2 * DD);
  finalize_kernel<<<1, 256, 0, stream>>>(p0, nb0, w0, p1, nb1, w1, p2, nb2, w2, lossp);
}